// Round 3
// baseline (995.314 us; speedup 1.0000x reference)
//
#include <hip/hip_runtime.h>
#include <hip/hip_bf16.h>

typedef unsigned short u16;
typedef unsigned int u32;
typedef __attribute__((ext_vector_type(8))) short bf16x8;
typedef __attribute__((ext_vector_type(4))) float f32x4;
typedef __attribute__((ext_vector_type(4))) u16 u16x4;

__device__ __forceinline__ float bf2f(u16 u){ return __uint_as_float(((u32)u) << 16); }
__device__ __forceinline__ u16 f2bf(float f){
  u32 u = __float_as_uint(f);
  u += 0x7fffu + ((u >> 16) & 1u);
  return (u16)(u >> 16);
}
__device__ __forceinline__ void gll16(const u16* g, u16* l){
  __builtin_amdgcn_global_load_lds((const __attribute__((address_space(1))) u32*)g,
                                   (__attribute__((address_space(3))) u32*)l, 16, 0, 0);
}

#define MFMA16(a,b,c) __builtin_amdgcn_mfma_f32_16x16x32_bf16((a),(b),(c),0,0,0)

// ---------------- fp32 -> bf16 hi (+ optional lo residual) ----------------
template<bool LO>
__global__ __launch_bounds__(256) void split_fp32(const float* __restrict__ in,
                                                  u16* __restrict__ hi, u16* __restrict__ lo){
  const size_t i = ((size_t)blockIdx.x*256 + threadIdx.x)*8;
  u16 h[8], l[8];
  #pragma unroll
  for (int j=0;j<8;j++){
    const float v = in[i+j];
    h[j] = f2bf(v);
    if (LO) l[j] = f2bf(v - bf2f(h[j]));
  }
  *(bf16x8*)(hi+i) = *(bf16x8*)h;
  if (LO) *(bf16x8*)(lo+i) = *(bf16x8*)l;
}

// ---------------- transpose 2048x2048 fp32 -> bf16 hi (+lo), B^T form ----------------
template<bool LO>
__global__ __launch_bounds__(256) void transpose_w(const float* __restrict__ in,
                                                   u16* __restrict__ oh, u16* __restrict__ ol){
  __shared__ float tile[64*68];
  const int t = threadIdx.x;
  const int r0 = blockIdx.y*64, c0 = blockIdx.x*64;
  #pragma unroll
  for (int p=0;p<2;p++){
    const int row = p*32 + (t>>3), cg = (t&7)*8;
    const float* s = in + (size_t)(r0+row)*2048 + c0 + cg;
    #pragma unroll
    for (int j=0;j<8;j++) tile[row*68 + cg + j] = s[j];
  }
  __syncthreads();
  #pragma unroll
  for (int p=0;p<2;p++){
    const int orow = p*32 + (t>>3), cg = (t&7)*8;
    u16 h[8], l[8];
    #pragma unroll
    for (int j=0;j<8;j++){
      const float v = tile[(cg+j)*68 + orow];
      h[j] = f2bf(v);
      if (LO) l[j] = f2bf(v - bf2f(h[j]));
    }
    *(bf16x8*)(oh + (size_t)(c0+orow)*2048 + r0 + cg) = *(bf16x8*)h;
    if (LO) *(bf16x8*)(ol + (size_t)(c0+orow)*2048 + r0 + cg) = *(bf16x8*)l;
  }
}

// ---------------- q/k GEMM: C = A*B^T (split precision) + fused RMSNorm + hi/lo store ----
// PASSES: 1 = Ah*Bh; 2 = + Ah*Bl; 3 = + Al*Bh.  Tile 128x128, one head per N-tile.
template<int PASSES>
__global__ __launch_bounds__(256) void gemm_qk(const u16* __restrict__ Ah, const u16* __restrict__ Al,
                                               const u16* __restrict__ Bh, const u16* __restrict__ Bl,
                                               const float* __restrict__ scale,
                                               u16* __restrict__ Oh, u16* __restrict__ Ol){
  constexpr int K = 2048, N = 2048;
  __shared__ __align__(16) u16 AsH[128*32];
  __shared__ __align__(16) u16 BsH[128*32];
  __shared__ __align__(16) u16 AsL[128*32];
  __shared__ __align__(16) u16 BsL[128*32];
  __shared__ float red[2][2][64];
  const int t = threadIdx.x;
  const int lane = t & 63, w = t >> 6;
  const int wm = w & 1, wn = w >> 1;
  const int l15 = lane & 15, l4 = lane >> 4;
  const int m0 = blockIdx.y * 128, n0 = blockIdx.x * 128;
  f32x4 acc[4][4] = {};

  const size_t goff = (size_t)(t>>2)*K + (t&3)*8;
  const u16* gah = Ah + (size_t)m0*K + goff;
  const u16* gbh = Bh + (size_t)n0*K + goff;
  const u16* gal = (PASSES>=3) ? Al + (size_t)m0*K + goff : nullptr;
  const u16* gbl = (PASSES>=2) ? Bl + (size_t)n0*K + goff : nullptr;
  u16* lsOff0 = (u16*)0 + (size_t)(w*64)*8;
  u16* lsOff1 = (u16*)0 + (size_t)(256 + w*64)*8;
  const size_t fo = (size_t)(l15)*32 + l4*8;
  const u16* fAh = AsH + (size_t)(wm*64)*32 + fo;
  const u16* fBh = BsH + (size_t)(wn*64)*32 + fo;
  const u16* fAl = AsL + (size_t)(wm*64)*32 + fo;
  const u16* fBl = BsL + (size_t)(wn*64)*32 + fo;

  for (int kt = 0; kt < K; kt += 32){
    gll16(gah + kt, AsH + (lsOff0 - (u16*)0));
    gll16(gah + kt + (size_t)64*K, AsH + (lsOff1 - (u16*)0));
    gll16(gbh + kt, BsH + (lsOff0 - (u16*)0));
    gll16(gbh + kt + (size_t)64*K, BsH + (lsOff1 - (u16*)0));
    if (PASSES>=2){
      gll16(gbl + kt, BsL + (lsOff0 - (u16*)0));
      gll16(gbl + kt + (size_t)64*K, BsL + (lsOff1 - (u16*)0));
    }
    if (PASSES>=3){
      gll16(gal + kt, AsL + (lsOff0 - (u16*)0));
      gll16(gal + kt + (size_t)64*K, AsL + (lsOff1 - (u16*)0));
    }
    __syncthreads();
    bf16x8 ah[4], bh[4];
    #pragma unroll
    for (int i=0;i<4;i++) ah[i] = *(const bf16x8*)(fAh + i*16*32);
    #pragma unroll
    for (int j=0;j<4;j++) bh[j] = *(const bf16x8*)(fBh + j*16*32);
    #pragma unroll
    for (int i=0;i<4;i++)
      #pragma unroll
      for (int j=0;j<4;j++)
        acc[i][j] = MFMA16(ah[i], bh[j], acc[i][j]);
    if (PASSES>=2){
      bf16x8 bl[4];
      #pragma unroll
      for (int j=0;j<4;j++) bl[j] = *(const bf16x8*)(fBl + j*16*32);
      #pragma unroll
      for (int i=0;i<4;i++)
        #pragma unroll
        for (int j=0;j<4;j++)
          acc[i][j] = MFMA16(ah[i], bl[j], acc[i][j]);
    }
    if (PASSES>=3){
      bf16x8 al[4];
      #pragma unroll
      for (int i=0;i<4;i++) al[i] = *(const bf16x8*)(fAl + i*16*32);
      #pragma unroll
      for (int i=0;i<4;i++)
        #pragma unroll
        for (int j=0;j<4;j++)
          acc[i][j] = MFMA16(al[i], bh[j], acc[i][j]);
    }
    __syncthreads();
  }

  // fused RMSNorm over the 128 cols (= one full head dim) of each row
  float sc[4];
  #pragma unroll
  for (int j=0;j<4;j++) sc[j] = scale[wn*64 + j*16 + l15];
  #pragma unroll
  for (int i=0;i<4;i++){
    #pragma unroll
    for (int r=0;r<4;r++){
      float p = acc[i][0][r]*acc[i][0][r] + acc[i][1][r]*acc[i][1][r]
              + acc[i][2][r]*acc[i][2][r] + acc[i][3][r]*acc[i][3][r];
      #pragma unroll
      for (int d=1; d<16; d<<=1) p += __shfl_xor(p, d, 64);
      if (l15 == 0) red[wm][wn][i*16 + l4*4 + r] = p;
    }
  }
  __syncthreads();
  #pragma unroll
  for (int i=0;i<4;i++){
    #pragma unroll
    for (int r=0;r<4;r++){
      const int rl = i*16 + l4*4 + r;
      const float inv = rsqrtf((red[wm][0][rl] + red[wm][1][rl])*(1.f/128.f) + 1e-6f);
      const size_t grow = (size_t)(m0 + wm*64 + rl);
      #pragma unroll
      for (int j=0;j<4;j++){
        const size_t idx = grow*N + (n0 + wn*64 + j*16 + l15);
        const float v = acc[i][j][r]*inv*sc[j];
        const u16 h = f2bf(v);
        Oh[idx] = h;
        Ol[idx] = f2bf(v - bf2f(h));
      }
    }
  }
}

// ---------------- plain GEMM NT (single pass). EPI=1: V-transpose bf16; EPI=2: fp32 out ----
template<int EPI>
__global__ __launch_bounds__(256) void gemm_nt(const u16* __restrict__ A,
                                               const u16* __restrict__ Bt,
                                               u16* __restrict__ C,
                                               float* __restrict__ Cf){
  constexpr int K = 2048, N = 2048;
  __shared__ __align__(16) u16 As[128*32];
  __shared__ __align__(16) u16 Bs[128*32];
  const int t = threadIdx.x;
  const int lane = t & 63, w = t >> 6;
  const int wm = w & 1, wn = w >> 1;
  const int l15 = lane & 15, l4 = lane >> 4;
  const int m0 = blockIdx.y * 128, n0 = blockIdx.x * 128;
  f32x4 acc[4][4] = {};

  const u16* ga = A  + (size_t)(m0 + (t>>2))*K + (t&3)*8;
  const u16* gb = Bt + (size_t)(n0 + (t>>2))*K + (t&3)*8;
  u16* lA0 = As + (size_t)(w*64)*8;
  u16* lA1 = As + (size_t)(256 + w*64)*8;
  u16* lB0 = Bs + (size_t)(w*64)*8;
  u16* lB1 = Bs + (size_t)(256 + w*64)*8;
  const u16* fA = As + (size_t)(wm*64 + l15)*32 + l4*8;
  const u16* fB = Bs + (size_t)(wn*64 + l15)*32 + l4*8;

  for (int kt = 0; kt < K; kt += 32){
    gll16(ga + kt, lA0);
    gll16(ga + kt + (size_t)64*K, lA1);
    gll16(gb + kt, lB0);
    gll16(gb + kt + (size_t)64*K, lB1);
    __syncthreads();
    bf16x8 af[4], bfr[4];
    #pragma unroll
    for (int i=0;i<4;i++) af[i]  = *(const bf16x8*)(fA + i*16*32);
    #pragma unroll
    for (int j=0;j<4;j++) bfr[j] = *(const bf16x8*)(fB + j*16*32);
    #pragma unroll
    for (int i=0;i<4;i++)
      #pragma unroll
      for (int j=0;j<4;j++)
        acc[i][j] = MFMA16(af[i], bfr[j], acc[i][j]);
    __syncthreads();
  }

  if (EPI == 1){
    // rows m = b*2048+s, cols n = h*128+d -> vt[((b*16+h)*128+d)*2048 + s]
    #pragma unroll
    for (int i=0;i<4;i++){
      const int m = m0 + wm*64 + i*16 + l4*4;
      const int b = m >> 11, s = m & 2047;
      #pragma unroll
      for (int j=0;j<4;j++){
        const int n = n0 + wn*64 + j*16 + l15;
        u16x4 pk;
        pk.x = f2bf(acc[i][j][0]); pk.y = f2bf(acc[i][j][1]);
        pk.z = f2bf(acc[i][j][2]); pk.w = f2bf(acc[i][j][3]);
        *(u16x4*)&C[((size_t)(b*16 + (n>>7))*128 + (n&127))*2048 + s] = pk;
      }
    }
  } else {
    #pragma unroll
    for (int i=0;i<4;i++){
      const int r0 = m0 + wm*64 + i*16 + l4*4;
      #pragma unroll
      for (int j=0;j<4;j++){
        const int c = n0 + wn*64 + j*16 + l15;
        #pragma unroll
        for (int r=0;r<4;r++)
          Cf[(size_t)(r0+r)*N + c] = acc[i][j][r];
      }
    }
  }
}

// ---------------- Flash attention, split-precision QK^T ----------------
// Q,K hi/lo in [B,S,H,Dh]; V in [B,H,Dh,S]; out ctx bf16 [B,S,H,Dh]
__global__ __launch_bounds__(256) void attn_fwd(const u16* __restrict__ Qh_, const u16* __restrict__ Ql_,
                                                const u16* __restrict__ Kh_, const u16* __restrict__ Kl_,
                                                const u16* __restrict__ Vt, u16* __restrict__ O){
  __shared__ __align__(16) u16 KshH[64*128];
  __shared__ __align__(16) u16 KshL[64*128];
  __shared__ __align__(16) u16 Vsh[128*64];
  __shared__ __align__(16) u16 Psh[4][16*72];
  const int t = threadIdx.x;
  const int lane = t & 63, w = t >> 6;
  const int l15 = lane & 15, l4 = lane >> 4;
  const int bh = blockIdx.y;
  const int b = bh >> 4, h = bh & 15;
  const int q0 = blockIdx.x*64 + w*16;

  bf16x8 qh[4], ql[4];
  {
    const size_t qoff = ((size_t)((b<<11) + q0 + l15)*16 + h)*128 + l4*8;
    #pragma unroll
    for (int kk=0;kk<4;kk++){
      qh[kk] = *(const bf16x8*)(Qh_ + qoff + kk*32);
      ql[kk] = *(const bf16x8*)(Ql_ + qoff + kk*32);
    }
  }
  f32x4 oacc[8] = {};
  float mrun[4], lrun[4];
  #pragma unroll
  for (int r=0;r<4;r++){ mrun[r] = -INFINITY; lrun[r] = 0.f; }

  for (int kt = 0; kt < 2048; kt += 64){
    #pragma unroll
    for (int p=0;p<4;p++){
      const int g = p*256 + t, kr = g>>4, c16 = g&15;
      const size_t src = ((size_t)((b<<11) + kt + kr)*16 + h)*128 + c16*8;
      const int dst = kr*128 + ((c16 ^ (kr&7))*8);
      *(bf16x8*)&KshH[dst] = *(const bf16x8*)(Kh_ + src);
      *(bf16x8*)&KshL[dst] = *(const bf16x8*)(Kl_ + src);
    }
    #pragma unroll
    for (int p=0;p<4;p++){
      const int g = p*256 + t, vr = g>>3, c8 = g&7;
      bf16x8 v = *(const bf16x8*)(Vt + (((size_t)(b*16 + h)*128 + vr)<<11) + kt + c8*8);
      *(bf16x8*)&Vsh[vr*64 + ((c8 ^ (vr&7))*8)] = v;
    }
    __syncthreads();

    // S = Q K^T (3-term split): 16q x 64k per wave
    f32x4 sa[4] = {};
    #pragma unroll
    for (int ks=0;ks<4;ks++){
      const int row = ks*16 + l15;
      #pragma unroll
      for (int kk=0;kk<4;kk++){
        const int off = row*128 + (((kk*4 + l4) ^ (row&7))*8);
        bf16x8 khf = *(const bf16x8*)&KshH[off];
        bf16x8 klf = *(const bf16x8*)&KshL[off];
        sa[ks] = MFMA16(qh[kk], khf, sa[ks]);
        sa[ks] = MFMA16(ql[kk], khf, sa[ks]);
        sa[ks] = MFMA16(qh[kk], klf, sa[ks]);
      }
    }
    // online softmax
    float pe[4][4];
    #pragma unroll
    for (int r=0;r<4;r++){
      float mx = fmaxf(fmaxf(sa[0][r], sa[1][r]), fmaxf(sa[2][r], sa[3][r]));
      #pragma unroll
      for (int d=1; d<16; d<<=1) mx = fmaxf(mx, __shfl_xor(mx, d, 64));
      const float mnew = fmaxf(mrun[r], mx);
      const float corr = __expf(mrun[r] - mnew);
      float rs = 0.f;
      #pragma unroll
      for (int ks=0;ks<4;ks++){ const float e = __expf(sa[ks][r] - mnew); pe[ks][r] = e; rs += e; }
      #pragma unroll
      for (int d=1; d<16; d<<=1) rs += __shfl_xor(rs, d, 64);
      lrun[r] = lrun[r]*corr + rs;
      mrun[r] = mnew;
      #pragma unroll
      for (int n=0;n<8;n++) oacc[n][r] *= corr;
    }
    #pragma unroll
    for (int ks=0;ks<4;ks++)
      #pragma unroll
      for (int r=0;r<4;r++)
        Psh[w][(l4*4 + r)*72 + ks*16 + l15] = f2bf(pe[ks][r]);
    asm volatile("s_waitcnt lgkmcnt(0)" ::: "memory");

    #pragma unroll
    for (int ks2=0;ks2<2;ks2++){
      bf16x8 pa = *(const bf16x8*)&Psh[w][l15*72 + ks2*32 + l4*8];
      #pragma unroll
      for (int n=0;n<8;n++){
        const int row = n*16 + l15;
        const int c8 = ks2*4 + l4;
        bf16x8 vb = *(const bf16x8*)&Vsh[row*64 + ((c8 ^ (row&7))*8)];
        oacc[n] = MFMA16(pa, vb, oacc[n]);
      }
    }
    __syncthreads();
  }
  #pragma unroll
  for (int n=0;n<8;n++){
    const int d = n*16 + l15;
    #pragma unroll
    for (int r=0;r<4;r++){
      const int s = q0 + l4*4 + r;
      O[((size_t)((b<<11) + s)*16 + h)*128 + d] = f2bf(oacc[n][r] / lrun[r]);
    }
  }
}

extern "C" void kernel_launch(void* const* d_in, const int* in_sizes, int n_in,
                              void* d_out, int out_size, void* d_ws, size_t ws_size,
                              hipStream_t stream){
  const float* f_inq = (const float*)d_in[0];
  const float* f_inkv= (const float*)d_in[1];
  const float* f_Wq  = (const float*)d_in[2];
  const float* f_Wk  = (const float*)d_in[3];
  const float* f_Wv  = (const float*)d_in[4];
  const float* scq   = (const float*)d_in[5];
  const float* sck   = (const float*)d_in[6];
  const float* f_Wo  = (const float*)d_in[7];

  u16* ws = (u16*)d_ws;
  const size_t ACT = (size_t)16777216;   // 4*2048*16*128
  const size_t WEL = (size_t)4194304;    // 2048*2048
  u16* q_h = ws;
  u16* q_l = q_h + ACT;
  u16* k_h = q_l + ACT;
  u16* k_l = k_h + ACT;
  u16* v_t = k_l + ACT;
  u16* ctx = v_t + ACT;
  u16* wbase = ctx + ACT;

  // input-hi staging lives in d_out (exactly 2*ACT bf16), overwritten by final fp32 GEMM
  u16* inq_hi  = (u16*)d_out;
  u16* inkv_hi = inq_hi + ACT;

  const size_t needA = (8*ACT + 6*WEL)*2;  // 318,767,104 : inputs+weights+postnorm split
  const size_t needB = (6*ACT + 6*WEL)*2;  // 251,658,240 : weights+postnorm split
  const int tier = (ws_size >= needA) ? 3 : (ws_size >= needB ? 2 : 1);

  u16 *wq_h, *wq_l = nullptr, *wk_h, *wk_l = nullptr, *wv, *wo;
  u16 *inq_lo = nullptr, *inkv_lo = nullptr;
  if (tier >= 2){
    wq_h = wbase;          wq_l = wbase + WEL;
    wk_h = wbase + 2*WEL;  wk_l = wbase + 3*WEL;
    wv   = wbase + 4*WEL;  wo   = wbase + 5*WEL;
  } else {
    wq_h = wbase;          wk_h = wbase + WEL;
    wv   = wbase + 2*WEL;  wo   = wbase + 3*WEL;
  }
  if (tier == 3){ inq_lo = wbase + 6*WEL; inkv_lo = inq_lo + ACT; }

  if (tier == 3){
    split_fp32<true><<<8192, 256, 0, stream>>>(f_inq,  inq_hi,  inq_lo);
    split_fp32<true><<<8192, 256, 0, stream>>>(f_inkv, inkv_hi, inkv_lo);
  } else {
    split_fp32<false><<<8192, 256, 0, stream>>>(f_inq,  inq_hi,  nullptr);
    split_fp32<false><<<8192, 256, 0, stream>>>(f_inkv, inkv_hi, nullptr);
  }

  dim3 tg(32,32);
  if (tier >= 2){
    transpose_w<true><<<tg, 256, 0, stream>>>(f_Wq, wq_h, wq_l);
    transpose_w<true><<<tg, 256, 0, stream>>>(f_Wk, wk_h, wk_l);
  } else {
    transpose_w<false><<<tg, 256, 0, stream>>>(f_Wq, wq_h, nullptr);
    transpose_w<false><<<tg, 256, 0, stream>>>(f_Wk, wk_h, nullptr);
  }
  transpose_w<false><<<tg, 256, 0, stream>>>(f_Wv, wv, nullptr);
  transpose_w<false><<<tg, 256, 0, stream>>>(f_Wo, wo, nullptr);

  dim3 gg(16, 64);   // N/128, M/128
  if (tier == 3){
    gemm_qk<3><<<gg, 256, 0, stream>>>(inq_hi,  inq_lo,  wq_h, wq_l, scq, q_h, q_l);
    gemm_qk<3><<<gg, 256, 0, stream>>>(inkv_hi, inkv_lo, wk_h, wk_l, sck, k_h, k_l);
  } else if (tier == 2){
    gemm_qk<2><<<gg, 256, 0, stream>>>(inq_hi,  nullptr, wq_h, wq_l, scq, q_h, q_l);
    gemm_qk<2><<<gg, 256, 0, stream>>>(inkv_hi, nullptr, wk_h, wk_l, sck, k_h, k_l);
  } else {
    gemm_qk<1><<<gg, 256, 0, stream>>>(inq_hi,  nullptr, wq_h, nullptr, scq, q_h, q_l);
    gemm_qk<1><<<gg, 256, 0, stream>>>(inkv_hi, nullptr, wk_h, nullptr, sck, k_h, k_l);
  }
  gemm_nt<1><<<gg, 256, 0, stream>>>(inkv_hi, wv, v_t, nullptr);

  attn_fwd<<<dim3(32, 64), 256, 0, stream>>>(q_h, q_l, k_h, k_l, v_t, ctx);

  gemm_nt<2><<<gg, 256, 0, stream>>>(ctx, wo, nullptr, (float*)d_out);
}